// Round 2
// 705.618 us; speedup vs baseline: 1.0153x; 1.0153x over previous
//
#include <hip/hip_runtime.h>
#include <hip/hip_bf16.h>
#include <stdint.h>

#define NT   16384   // tokens = B*S
#define C_   768
#define DFF_ 3072
#define KX   3072    // N*C
#define NMIX 24
#define TB   64
#define KSPLIT 4
#define KSEG (KX / KSPLIT)   // 768

typedef __attribute__((ext_vector_type(8))) short shortx8;
typedef __attribute__((ext_vector_type(4))) float floatx4;

__device__ __forceinline__ short f2bf(float f) {
  union { float f; uint32_t u; } v; v.f = f;
  uint32_t r = v.u + 0x7fffu + ((v.u >> 16) & 1u);   // RNE
  return (short)(r >> 16);
}

__device__ __forceinline__ float bf2f(short s) {
  union { uint32_t u; float f; } v;
  v.u = ((uint32_t)(uint16_t)s) << 16;
  return v.f;
}

// fast gelu: v*sigmoid(1.5957691*(v+0.044715 v^3)); |err| vs erf-gelu ~3e-4
__device__ __forceinline__ float gelu_f(float v) {
  float u = 1.5957691216057308f * v * (1.0f + 0.044715f * v * v);
  return v / (1.0f + __expf(-u));
}

// ---------- prep: phi (3072x24) -> phiT (24x3072) fp32 ----------
__global__ void phiT_kernel(const float* __restrict__ phi, float* __restrict__ phiT) {
  int idx = blockIdx.x * 256 + threadIdx.x;
  if (idx < KX * NMIX) {
    int k = idx / NMIX, j = idx - k * NMIX;
    phiT[(size_t)j * KX + k] = phi[idx];
  }
}

// ---------- prep: fp32 (R x C) -> bf16 transposed (C x R) ----------
__global__ __launch_bounds__(256) void transpose_bf16(const float* __restrict__ in,
                                                      short* __restrict__ out,
                                                      int R, int C) {
  __shared__ float tile[32][33];
  int bx = blockIdx.x * 32;   // C dim
  int by = blockIdx.y * 32;   // R dim
  int tx = threadIdx.x & 31, ty = threadIdx.x >> 5;
  #pragma unroll
  for (int i = 0; i < 32; i += 8)
    tile[ty + i][tx] = in[(size_t)(by + ty + i) * C + bx + tx];
  __syncthreads();
  #pragma unroll
  for (int i = 0; i < 32; i += 8)
    out[(size_t)(bx + ty + i) * R + by + tx] = f2bf(tile[tx][ty + i]);
}

// ---------- k1a: partial mix + partial ssq over a 768-wide k segment ----------
__global__ __launch_bounds__(256) void k1a(
    const float* __restrict__ x, const float* __restrict__ phiT,
    float* __restrict__ pmix, float* __restrict__ pssq) {
  __shared__ float xs[TB][132];     // 128-k chunk, +4 pad
  int tid = threadIdx.x;
  int lane = tid & 63;              // token within block
  int w = tid >> 6;                 // j-group (6 j's per wave)
  int wu = __builtin_amdgcn_readfirstlane(w);
  int t0 = (blockIdx.x >> 2) * TB;
  int slot = blockIdx.x & 3;
  int ks = slot * KSEG;

  float acc[6] = {0.f, 0.f, 0.f, 0.f, 0.f, 0.f};
  float ssq = 0.f;

  for (int kc = ks; kc < ks + KSEG; kc += 128) {
    if (kc != ks) __syncthreads();
    #pragma unroll
    for (int jj = 0; jj < 8; ++jj) {          // stage 64 tokens x 128 k
      int idx = tid + jj * 256;
      int row = idx >> 5, c4 = idx & 31;
      const float4 v = *(const float4*)&x[(size_t)(t0 + row) * KX + kc + c4 * 4];
      *(float4*)&xs[row][c4 * 4] = v;
    }
    __syncthreads();
    #pragma unroll 4
    for (int k4 = 0; k4 < 32; ++k4) {
      const float4 xv = *(const float4*)&xs[lane][k4 * 4];
      if (w == 0) ssq += xv.x * xv.x + xv.y * xv.y + xv.z * xv.z + xv.w * xv.w;
      int kk = kc + k4 * 4;
      #pragma unroll
      for (int jj = 0; jj < 6; ++jj) {        // phi via wave-uniform (scalar) loads
        const float4 p = *(const float4*)&phiT[(size_t)(wu * 6 + jj) * KX + kk];
        acc[jj] += p.x * xv.x + p.y * xv.y + p.z * xv.z + p.w * xv.w;
      }
    }
  }
  if (w == 0) pssq[(size_t)(t0 + lane) * KSPLIT + slot] = ssq;
  #pragma unroll
  for (int jj = 0; jj < 6; ++jj)
    pmix[((size_t)(t0 + lane) * KSPLIT + slot) * NMIX + wu * 6 + jj] = acc[jj];
}

// ---------- k1b: reduce partials + sinkhorn + h_pre/h_post/h_res ----------
__global__ __launch_bounds__(256) void k1b(
    const float* __restrict__ pmix, const float* __restrict__ pssq,
    const float* __restrict__ bvec, const float* __restrict__ a_pre,
    const float* __restrict__ a_post, const float* __restrict__ a_res,
    float* __restrict__ hpre, float* __restrict__ hpost, float* __restrict__ hres) {
  __shared__ float mixs[TB][NMIX];
  __shared__ float invr_s[TB];
  int tid = threadIdx.x;
  int t0 = blockIdx.x * TB;
  int tq = tid >> 2, r = tid & 3;

  {   // thread (tq, r) reduces j-range [r*6, r*6+6) over 4 k-slots
    const float* pm = pmix + (size_t)(t0 + tq) * KSPLIT * NMIX;
    float s[6] = {0.f, 0.f, 0.f, 0.f, 0.f, 0.f};
    #pragma unroll
    for (int sl = 0; sl < KSPLIT; ++sl)
      #pragma unroll
      for (int jj = 0; jj < 6; ++jj)
        s[jj] += pm[sl * NMIX + r * 6 + jj];
    #pragma unroll
    for (int jj = 0; jj < 6; ++jj) mixs[tq][r * 6 + jj] = s[jj];
    if (r == 0) {
      const float* ps = pssq + (size_t)(t0 + tq) * KSPLIT;
      float sq = ps[0] + ps[1] + ps[2] + ps[3];
      invr_s[tq] = rsqrtf(sq * (1.0f / KX) + 1e-6f);
    }
  }
  __syncthreads();

  {  // sinkhorn: thread = (token tq, row r); cols in regs, col-sums via shfl
    float invr = invr_s[tq];
    float ares = a_res[0];
    float v0 = mixs[tq][8 + r * 4 + 0] * invr * ares + bvec[8 + r * 4 + 0];
    float v1 = mixs[tq][8 + r * 4 + 1] * invr * ares + bvec[8 + r * 4 + 1];
    float v2 = mixs[tq][8 + r * 4 + 2] * invr * ares + bvec[8 + r * 4 + 2];
    float v3 = mixs[tq][8 + r * 4 + 3] * invr * ares + bvec[8 + r * 4 + 3];
    float mx = fmaxf(fmaxf(v0, v1), fmaxf(v2, v3));
    v0 = __expf(v0 - mx); v1 = __expf(v1 - mx); v2 = __expf(v2 - mx); v3 = __expf(v3 - mx);
    for (int it = 0; it < 20; ++it) {
      float s = v0 + v1 + v2 + v3 + 1e-6f;    // row normalize (ref adds eps to sum)
      float inv = 1.0f / s;
      v0 *= inv; v1 *= inv; v2 *= inv; v3 *= inv;
      float c0 = v0 + __shfl_xor(v0, 1); c0 += __shfl_xor(c0, 2);
      float c1 = v1 + __shfl_xor(v1, 1); c1 += __shfl_xor(c1, 2);
      float c2 = v2 + __shfl_xor(v2, 1); c2 += __shfl_xor(c2, 2);
      float c3 = v3 + __shfl_xor(v3, 1); c3 += __shfl_xor(c3, 2);
      v0 /= (c0 + 1e-6f); v1 /= (c1 + 1e-6f); v2 /= (c2 + 1e-6f); v3 /= (c3 + 1e-6f);
    }
    float* ho = hres + (size_t)(t0 + tq) * 16 + r * 4;
    ho[0] = v0; ho[1] = v1; ho[2] = v2; ho[3] = v3;
    if (r == 0) {
      float apre = a_pre[0];
      float4 hp;
      hp.x = 1.0f / (1.0f + __expf(-(mixs[tq][0] * invr * apre + bvec[0])));
      hp.y = 1.0f / (1.0f + __expf(-(mixs[tq][1] * invr * apre + bvec[1])));
      hp.z = 1.0f / (1.0f + __expf(-(mixs[tq][2] * invr * apre + bvec[2])));
      hp.w = 1.0f / (1.0f + __expf(-(mixs[tq][3] * invr * apre + bvec[3])));
      *(float4*)&hpre[(size_t)(t0 + tq) * 4] = hp;
    } else if (r == 1) {
      float apost = a_post[0];
      float4 hq;
      hq.x = 2.0f / (1.0f + __expf(-(mixs[tq][4] * invr * apost + bvec[4])));
      hq.y = 2.0f / (1.0f + __expf(-(mixs[tq][5] * invr * apost + bvec[5])));
      hq.z = 2.0f / (1.0f + __expf(-(mixs[tq][6] * invr * apost + bvec[6])));
      hq.w = 2.0f / (1.0f + __expf(-(mixs[tq][7] * invr * apost + bvec[7])));
      *(float4*)&hpost[(size_t)(t0 + tq) * 4] = hq;
    }
  }
}

// ---------- k1c: x_in[t][c] = sum_n hpre[t][n] * x[t][n*768+c], bf16 out ----------
__global__ __launch_bounds__(256) void k1c(
    const float* __restrict__ x, const float* __restrict__ hpre,
    short* __restrict__ x_in) {
  int idx = blockIdx.x * 256 + threadIdx.x;   // NT*192 float4-groups
  int t = idx / 192;
  int c = (idx - t * 192) * 4;
  float4 hp = *(const float4*)&hpre[(size_t)t * 4];
  const float* xr = x + (size_t)t * KX + c;
  float4 x0 = *(const float4*)(xr);
  float4 x1 = *(const float4*)(xr + C_);
  float4 x2 = *(const float4*)(xr + 2 * C_);
  float4 x3 = *(const float4*)(xr + 3 * C_);
  short4 s;
  s.x = f2bf(hp.x * x0.x + hp.y * x1.x + hp.z * x2.x + hp.w * x3.x);
  s.y = f2bf(hp.x * x0.y + hp.y * x1.y + hp.z * x2.y + hp.w * x3.y);
  s.z = f2bf(hp.x * x0.z + hp.y * x1.z + hp.z * x2.z + hp.w * x3.z);
  s.w = f2bf(hp.x * x0.w + hp.y * x1.w + hp.z * x2.w + hp.w * x3.w);
  *(short4*)&x_in[(size_t)t * C_ + c] = s;
}

// ---------- m97-style bf16 GEMM, B^T input, fused epilogues ----------
// Both epilogues stage the 128x128 result tile as bf16 in LDS (single pass,
// all waves, one barrier, padded rows, no swizzle), then drain coalesced.
// EPI=1: act = gelu(A@B^T + bias), bf16, shortx8 stores
// EPI=2: out[t,n,:] = hres@x + hpost*(A@B^T + bias), f32, float4 I/O
template <int EPI>
__global__ __launch_bounds__(256, 3) void gemm_bt(
    const short* __restrict__ A, const short* __restrict__ B,
    int M, int N, int K, const float* __restrict__ bias,
    short* __restrict__ outb,
    const float* __restrict__ x, const float* __restrict__ hres,
    const float* __restrict__ hpost, float* __restrict__ out) {
  __shared__ short As[128 * 32];
  __shared__ short Bs[128 * 32];
  __shared__ __align__(16) short cb[128 * 136];   // 34816 B restage tile (+8 pad)
  int tid = threadIdx.x;
  int lane = tid & 63, w = tid >> 6;
  int m0 = blockIdx.y * 128, n0 = blockIdx.x * 128;
  int wm = (w >> 1) * 64, wn = (w & 1) * 64;
  int lrow = lane & 15, quad = lane >> 4;
  floatx4 acc[4][4] = {};

  for (int k0 = 0; k0 < K; k0 += 32) {
    if (k0) __syncthreads();
    #pragma unroll
    for (int i = 0; i < 2; ++i) {
      int c = tid + i * 256;
      int row = c >> 2, slot = c & 3;
      const short* ga = A + (size_t)(m0 + row) * K + k0 + slot * 8;
      const short* gb = B + (size_t)(n0 + row) * K + k0 + slot * 8;
      __builtin_amdgcn_global_load_lds((const __attribute__((address_space(1))) void*)ga,
                                       (__attribute__((address_space(3))) void*)&As[c * 8],
                                       16, 0, 0);
      __builtin_amdgcn_global_load_lds((const __attribute__((address_space(1))) void*)gb,
                                       (__attribute__((address_space(3))) void*)&Bs[c * 8],
                                       16, 0, 0);
    }
    __syncthreads();
    shortx8 af[4], bfr[4];
    #pragma unroll
    for (int mi = 0; mi < 4; ++mi)
      af[mi] = *(const shortx8*)&As[(wm + mi * 16 + lrow) * 32 + quad * 8];
    #pragma unroll
    for (int ni = 0; ni < 4; ++ni)
      bfr[ni] = *(const shortx8*)&Bs[(wn + ni * 16 + lrow) * 32 + quad * 8];
    #pragma unroll
    for (int mi = 0; mi < 4; ++mi)
      #pragma unroll
      for (int ni = 0; ni < 4; ++ni)
        acc[mi][ni] = __builtin_amdgcn_mfma_f32_16x16x32_bf16(af[mi], bfr[ni], acc[mi][ni], 0, 0, 0);
  }

  float bcol[4];
  #pragma unroll
  for (int ni = 0; ni < 4; ++ni) bcol[ni] = bias[n0 + wn + ni * 16 + lrow];

  // ---- stage: identical (row,col,value) triples to the proven direct epilogue,
  //      destination is LDS instead of HBM. All waves, no conditionals. ----
  #pragma unroll
  for (int mi = 0; mi < 4; ++mi) {
    #pragma unroll
    for (int r = 0; r < 4; ++r) {
      int rr = wm + mi * 16 + quad * 4 + r;       // row within 128-tile
      #pragma unroll
      for (int ni = 0; ni < 4; ++ni) {
        int col = wn + ni * 16 + lrow;            // col within 128-tile
        float v = acc[mi][ni][r] + bcol[ni];
        if (EPI == 1) v = gelu_f(v);
        cb[rr * 136 + col] = f2bf(v);
      }
    }
  }
  __syncthreads();

  // ---- drain: 16 lanes per row, 8 bf16 each (256B LDS rows, coalesced HBM) ----
  int rbase = tid >> 4, ic = tid & 15;
  if (EPI == 1) {
    #pragma unroll
    for (int v = 0; v < 8; ++v) {
      int rr = v * 16 + rbase;
      shortx8 val = *(const shortx8*)&cb[rr * 136 + ic * 8];
      *(shortx8*)&outb[(size_t)(m0 + rr) * N + n0 + ic * 8] = val;
    }
  } else {
    #pragma unroll
    for (int v = 0; v < 8; ++v) {
      int rr = v * 16 + rbase;
      int tr = m0 + rr;
      shortx8 f8 = *(const shortx8*)&cb[rr * 136 + ic * 8];
      float fv[8];
      #pragma unroll
      for (int j = 0; j < 8; ++j) fv[j] = bf2f(f8[j]);
      const float* xr = x + (size_t)tr * KX + n0 + ic * 8;
      float4 xa[4], xb[4];
      #pragma unroll
      for (int n = 0; n < 4; ++n) {
        xa[n] = *(const float4*)(xr + n * 768);
        xb[n] = *(const float4*)(xr + n * 768 + 4);
      }
      const float4* hrp = (const float4*)(hres + (size_t)tr * 16);
      float4 hp4 = *(const float4*)&hpost[(size_t)tr * 4];
      float hpv[4] = {hp4.x, hp4.y, hp4.z, hp4.w};
      float* orow = out + (size_t)tr * KX + n0 + ic * 8;
      #pragma unroll
      for (int n = 0; n < 4; ++n) {
        float4 h = hrp[n];
        float4 oa, ob;
        oa.x = h.x * xa[0].x + h.y * xa[1].x + h.z * xa[2].x + h.w * xa[3].x + hpv[n] * fv[0];
        oa.y = h.x * xa[0].y + h.y * xa[1].y + h.z * xa[2].y + h.w * xa[3].y + hpv[n] * fv[1];
        oa.z = h.x * xa[0].z + h.y * xa[1].z + h.z * xa[2].z + h.w * xa[3].z + hpv[n] * fv[2];
        oa.w = h.x * xa[0].w + h.y * xa[1].w + h.z * xa[2].w + h.w * xa[3].w + hpv[n] * fv[3];
        ob.x = h.x * xb[0].x + h.y * xb[1].x + h.z * xb[2].x + h.w * xb[3].x + hpv[n] * fv[4];
        ob.y = h.x * xb[0].y + h.y * xb[1].y + h.z * xb[2].y + h.w * xb[3].y + hpv[n] * fv[5];
        ob.z = h.x * xb[0].z + h.y * xb[1].z + h.z * xb[2].z + h.w * xb[3].z + hpv[n] * fv[6];
        ob.w = h.x * xb[0].w + h.y * xb[1].w + h.z * xb[2].w + h.w * xb[3].w + hpv[n] * fv[7];
        *(float4*)(orow + n * 768) = oa;
        *(float4*)(orow + n * 768 + 4) = ob;
      }
    }
  }
}

extern "C" void kernel_launch(void* const* d_in, const int* in_sizes, int n_in,
                              void* d_out, int out_size, void* d_ws, size_t ws_size,
                              hipStream_t stream) {
  const float* x      = (const float*)d_in[0];
  const float* phi    = (const float*)d_in[1];
  const float* b      = (const float*)d_in[2];
  const float* a_pre  = (const float*)d_in[3];
  const float* a_post = (const float*)d_in[4];
  const float* a_res  = (const float*)d_in[5];
  const float* W1     = (const float*)d_in[6];
  const float* b1     = (const float*)d_in[7];
  const float* W2     = (const float*)d_in[8];
  const float* b2     = (const float*)d_in[9];
  float* out = (float*)d_out;

  char* ws = (char*)d_ws;
  size_t off = 0;
  auto carve = [&](size_t bytes) {
    char* p = ws + off;
    off += (bytes + 255) & ~(size_t)255;
    return p;
  };
  short* x_in  = (short*)carve((size_t)NT * C_ * 2);        //  25.2 MB bf16
  short* act   = (short*)carve((size_t)NT * DFF_ * 2);      // 100.7 MB bf16
  float* hpost = (float*)carve((size_t)NT * 4 * 4);
  float* hres  = (float*)carve((size_t)NT * 16 * 4);
  float* hpre  = (float*)carve((size_t)NT * 4 * 4);
  short* W1T   = (short*)carve((size_t)DFF_ * C_ * 2);
  short* W2T   = (short*)carve((size_t)C_ * DFF_ * 2);
  float* phiT  = (float*)carve((size_t)NMIX * KX * 4);
  float* pmix  = (float*)carve((size_t)NT * KSPLIT * NMIX * 4);  // 6.3 MB
  float* pssq  = (float*)carve((size_t)NT * KSPLIT * 4);

  phiT_kernel<<<dim3((KX * NMIX + 255) / 256), 256, 0, stream>>>(phi, phiT);
  transpose_bf16<<<dim3(DFF_ / 32, C_ / 32), 256, 0, stream>>>(W1, W1T, C_, DFF_);
  transpose_bf16<<<dim3(C_ / 32, DFF_ / 32), 256, 0, stream>>>(W2, W2T, DFF_, C_);
  k1a<<<dim3((NT / TB) * KSPLIT), 256, 0, stream>>>(x, phiT, pmix, pssq);
  k1b<<<dim3(NT / TB), 256, 0, stream>>>(pmix, pssq, b, a_pre, a_post, a_res,
                                         hpre, hpost, hres);
  k1c<<<dim3(NT * 192 / 256), 256, 0, stream>>>(x, hpre, x_in);
  gemm_bt<1><<<dim3(DFF_ / 128, NT / 128), 256, 0, stream>>>(
      x_in, W1T, NT, DFF_, C_, b1, act, nullptr, nullptr, nullptr, nullptr);
  gemm_bt<2><<<dim3(C_ / 128, NT / 128), 256, 0, stream>>>(
      act, W2T, NT, C_, DFF_, b2, nullptr, x, hres, hpost, out);
}

// Round 3
// 678.891 us; speedup vs baseline: 1.0553x; 1.0394x over previous
//
#include <hip/hip_runtime.h>
#include <hip/hip_bf16.h>
#include <stdint.h>

#define NT   16384   // tokens = B*S
#define C_   768
#define DFF_ 3072
#define KX   3072    // N*C
#define NMIX 24
#define TB   64
#define KSPLIT 4
#define KSEG (KX / KSPLIT)   // 768

typedef __attribute__((ext_vector_type(8))) short shortx8;
typedef __attribute__((ext_vector_type(4))) float floatx4;

__device__ __forceinline__ short f2bf(float f) {
  union { float f; uint32_t u; } v; v.f = f;
  uint32_t r = v.u + 0x7fffu + ((v.u >> 16) & 1u);   // RNE
  return (short)(r >> 16);
}

__device__ __forceinline__ float bf2f(short s) {
  union { uint32_t u; float f; } v;
  v.u = ((uint32_t)(uint16_t)s) << 16;
  return v.f;
}

// fast gelu: v*sigmoid(1.5957691*(v+0.044715 v^3)); |err| vs erf-gelu ~3e-4
__device__ __forceinline__ float gelu_f(float v) {
  float u = 1.5957691216057308f * v * (1.0f + 0.044715f * v * v);
  return v / (1.0f + __expf(-u));
}

// ---------- prep: phi (3072x24) -> phiT (24x3072) fp32 ----------
__global__ void phiT_kernel(const float* __restrict__ phi, float* __restrict__ phiT) {
  int idx = blockIdx.x * 256 + threadIdx.x;
  if (idx < KX * NMIX) {
    int k = idx / NMIX, j = idx - k * NMIX;
    phiT[(size_t)j * KX + k] = phi[idx];
  }
}

// ---------- prep: fp32 (R x C) -> bf16 transposed (C x R) ----------
__global__ __launch_bounds__(256) void transpose_bf16(const float* __restrict__ in,
                                                      short* __restrict__ out,
                                                      int R, int C) {
  __shared__ float tile[32][33];
  int bx = blockIdx.x * 32;   // C dim
  int by = blockIdx.y * 32;   // R dim
  int tx = threadIdx.x & 31, ty = threadIdx.x >> 5;
  #pragma unroll
  for (int i = 0; i < 32; i += 8)
    tile[ty + i][tx] = in[(size_t)(by + ty + i) * C + bx + tx];
  __syncthreads();
  #pragma unroll
  for (int i = 0; i < 32; i += 8)
    out[(size_t)(bx + ty + i) * R + by + tx] = f2bf(tile[tx][ty + i]);
}

// ---------- k1a: partial mix + partial ssq over a 768-wide k segment ----------
__global__ __launch_bounds__(256) void k1a(
    const float* __restrict__ x, const float* __restrict__ phiT,
    float* __restrict__ pmix, float* __restrict__ pssq) {
  __shared__ float xs[TB][132];     // 128-k chunk, +4 pad
  int tid = threadIdx.x;
  int lane = tid & 63;              // token within block
  int w = tid >> 6;                 // j-group (6 j's per wave)
  int wu = __builtin_amdgcn_readfirstlane(w);
  int t0 = (blockIdx.x >> 2) * TB;
  int slot = blockIdx.x & 3;
  int ks = slot * KSEG;

  float acc[6] = {0.f, 0.f, 0.f, 0.f, 0.f, 0.f};
  float ssq = 0.f;

  for (int kc = ks; kc < ks + KSEG; kc += 128) {
    if (kc != ks) __syncthreads();
    #pragma unroll
    for (int jj = 0; jj < 8; ++jj) {          // stage 64 tokens x 128 k
      int idx = tid + jj * 256;
      int row = idx >> 5, c4 = idx & 31;
      const float4 v = *(const float4*)&x[(size_t)(t0 + row) * KX + kc + c4 * 4];
      *(float4*)&xs[row][c4 * 4] = v;
    }
    __syncthreads();
    #pragma unroll 4
    for (int k4 = 0; k4 < 32; ++k4) {
      const float4 xv = *(const float4*)&xs[lane][k4 * 4];
      if (w == 0) ssq += xv.x * xv.x + xv.y * xv.y + xv.z * xv.z + xv.w * xv.w;
      int kk = kc + k4 * 4;
      #pragma unroll
      for (int jj = 0; jj < 6; ++jj) {        // phi via wave-uniform (scalar) loads
        const float4 p = *(const float4*)&phiT[(size_t)(wu * 6 + jj) * KX + kk];
        acc[jj] += p.x * xv.x + p.y * xv.y + p.z * xv.z + p.w * xv.w;
      }
    }
  }
  if (w == 0) pssq[(size_t)(t0 + lane) * KSPLIT + slot] = ssq;
  #pragma unroll
  for (int jj = 0; jj < 6; ++jj)
    pmix[((size_t)(t0 + lane) * KSPLIT + slot) * NMIX + wu * 6 + jj] = acc[jj];
}

// ---------- k1b: reduce partials + sinkhorn + h_pre/h_post/h_res ----------
__global__ __launch_bounds__(256) void k1b(
    const float* __restrict__ pmix, const float* __restrict__ pssq,
    const float* __restrict__ bvec, const float* __restrict__ a_pre,
    const float* __restrict__ a_post, const float* __restrict__ a_res,
    float* __restrict__ hpre, float* __restrict__ hpost, float* __restrict__ hres) {
  __shared__ float mixs[TB][NMIX];
  __shared__ float invr_s[TB];
  int tid = threadIdx.x;
  int t0 = blockIdx.x * TB;
  int tq = tid >> 2, r = tid & 3;

  {   // thread (tq, r) reduces j-range [r*6, r*6+6) over 4 k-slots
    const float* pm = pmix + (size_t)(t0 + tq) * KSPLIT * NMIX;
    float s[6] = {0.f, 0.f, 0.f, 0.f, 0.f, 0.f};
    #pragma unroll
    for (int sl = 0; sl < KSPLIT; ++sl)
      #pragma unroll
      for (int jj = 0; jj < 6; ++jj)
        s[jj] += pm[sl * NMIX + r * 6 + jj];
    #pragma unroll
    for (int jj = 0; jj < 6; ++jj) mixs[tq][r * 6 + jj] = s[jj];
    if (r == 0) {
      const float* ps = pssq + (size_t)(t0 + tq) * KSPLIT;
      float sq = ps[0] + ps[1] + ps[2] + ps[3];
      invr_s[tq] = rsqrtf(sq * (1.0f / KX) + 1e-6f);
    }
  }
  __syncthreads();

  {  // sinkhorn: thread = (token tq, row r); cols in regs, col-sums via shfl
    float invr = invr_s[tq];
    float ares = a_res[0];
    float v0 = mixs[tq][8 + r * 4 + 0] * invr * ares + bvec[8 + r * 4 + 0];
    float v1 = mixs[tq][8 + r * 4 + 1] * invr * ares + bvec[8 + r * 4 + 1];
    float v2 = mixs[tq][8 + r * 4 + 2] * invr * ares + bvec[8 + r * 4 + 2];
    float v3 = mixs[tq][8 + r * 4 + 3] * invr * ares + bvec[8 + r * 4 + 3];
    float mx = fmaxf(fmaxf(v0, v1), fmaxf(v2, v3));
    v0 = __expf(v0 - mx); v1 = __expf(v1 - mx); v2 = __expf(v2 - mx); v3 = __expf(v3 - mx);
    for (int it = 0; it < 20; ++it) {
      float s = v0 + v1 + v2 + v3 + 1e-6f;    // row normalize (ref adds eps to sum)
      float inv = 1.0f / s;
      v0 *= inv; v1 *= inv; v2 *= inv; v3 *= inv;
      float c0 = v0 + __shfl_xor(v0, 1); c0 += __shfl_xor(c0, 2);
      float c1 = v1 + __shfl_xor(v1, 1); c1 += __shfl_xor(c1, 2);
      float c2 = v2 + __shfl_xor(v2, 1); c2 += __shfl_xor(c2, 2);
      float c3 = v3 + __shfl_xor(v3, 1); c3 += __shfl_xor(c3, 2);
      v0 /= (c0 + 1e-6f); v1 /= (c1 + 1e-6f); v2 /= (c2 + 1e-6f); v3 /= (c3 + 1e-6f);
    }
    float* ho = hres + (size_t)(t0 + tq) * 16 + r * 4;
    ho[0] = v0; ho[1] = v1; ho[2] = v2; ho[3] = v3;
    if (r == 0) {
      float apre = a_pre[0];
      float4 hp;
      hp.x = 1.0f / (1.0f + __expf(-(mixs[tq][0] * invr * apre + bvec[0])));
      hp.y = 1.0f / (1.0f + __expf(-(mixs[tq][1] * invr * apre + bvec[1])));
      hp.z = 1.0f / (1.0f + __expf(-(mixs[tq][2] * invr * apre + bvec[2])));
      hp.w = 1.0f / (1.0f + __expf(-(mixs[tq][3] * invr * apre + bvec[3])));
      *(float4*)&hpre[(size_t)(t0 + tq) * 4] = hp;
    } else if (r == 1) {
      float apost = a_post[0];
      float4 hq;
      hq.x = 2.0f / (1.0f + __expf(-(mixs[tq][4] * invr * apost + bvec[4])));
      hq.y = 2.0f / (1.0f + __expf(-(mixs[tq][5] * invr * apost + bvec[5])));
      hq.z = 2.0f / (1.0f + __expf(-(mixs[tq][6] * invr * apost + bvec[6])));
      hq.w = 2.0f / (1.0f + __expf(-(mixs[tq][7] * invr * apost + bvec[7])));
      *(float4*)&hpost[(size_t)(t0 + tq) * 4] = hq;
    }
  }
}

// ---------- k1c: x_in[t][c] = sum_n hpre[t][n] * x[t][n*768+c], bf16 out ----------
__global__ __launch_bounds__(256) void k1c(
    const float* __restrict__ x, const float* __restrict__ hpre,
    short* __restrict__ x_in) {
  int idx = blockIdx.x * 256 + threadIdx.x;   // NT*192 float4-groups
  int t = idx / 192;
  int c = (idx - t * 192) * 4;
  float4 hp = *(const float4*)&hpre[(size_t)t * 4];
  const float* xr = x + (size_t)t * KX + c;
  float4 x0 = *(const float4*)(xr);
  float4 x1 = *(const float4*)(xr + C_);
  float4 x2 = *(const float4*)(xr + 2 * C_);
  float4 x3 = *(const float4*)(xr + 3 * C_);
  short4 s;
  s.x = f2bf(hp.x * x0.x + hp.y * x1.x + hp.z * x2.x + hp.w * x3.x);
  s.y = f2bf(hp.x * x0.y + hp.y * x1.y + hp.z * x2.y + hp.w * x3.y);
  s.z = f2bf(hp.x * x0.z + hp.y * x1.z + hp.z * x2.z + hp.w * x3.z);
  s.w = f2bf(hp.x * x0.w + hp.y * x1.w + hp.z * x2.w + hp.w * x3.w);
  *(short4*)&x_in[(size_t)t * C_ + c] = s;
}

// ---------- bf16 GEMM, B^T input, 2-phase double-buffered K-loop ----------
// Pipeline: stage(t+1) issued BEFORE compute(t); ONE barrier per K-step, so the
// vmcnt(0) drain lands after the MFMA phase instead of before it.
// LDS: dbuf As/Bs (32 KB) unioned with the 34.8 KB epilogue restage tile.
// EPI=1: act = gelu(A@B^T + bias), bf16, shortx8 stores
// EPI=2: out[t,n,:] = hres@x + hpost*(A@B^T + bias), f32, float4 I/O
template <int EPI>
__global__ __launch_bounds__(256, 3) void gemm_bt(
    const short* __restrict__ A, const short* __restrict__ B,
    int M, int N, int K, const float* __restrict__ bias,
    short* __restrict__ outb,
    const float* __restrict__ x, const float* __restrict__ hres,
    const float* __restrict__ hpost, float* __restrict__ out) {
  __shared__ __align__(16) char smem[34816];       // max(dbuf 32768, cb 34816)
  short* As = (short*)smem;                        // [2][4096] bf16
  short* Bs = (short*)(smem + 16384);              // [2][4096] bf16
  short* cb = (short*)smem;                        // epilogue 128x136 bf16
  int tid = threadIdx.x;
  int lane = tid & 63, w = tid >> 6;
  // XCD-chunked swizzle: consecutive lids (sharing the A-panel) on one XCD.
  int nwg = gridDim.x * gridDim.y;                 // 768 / 3072, both %8==0
  int lid = blockIdx.y * gridDim.x + blockIdx.x;
  int sid = (lid & 7) * (nwg >> 3) + (lid >> 3);   // bijective for nwg%8==0
  int bx = sid % gridDim.x, by = sid / gridDim.x;
  int m0 = by * 128, n0 = bx * 128;
  int wm = (w >> 1) * 64, wn = (w & 1) * 64;
  int lrow = lane & 15, quad = lane >> 4;
  floatx4 acc[4][4] = {};

  int srow = tid >> 2, sslot = tid & 3;            // staging: thread -> (row, 8-elem slot)
  int srow2 = (tid + 256) >> 2, sslot2 = (tid + 256) & 3;

  auto stage = [&](int buf, int k0) {
    const short* ga = A + (size_t)(m0 + srow) * K + k0 + sslot * 8;
    const short* gb = B + (size_t)(n0 + srow) * K + k0 + sslot * 8;
    __builtin_amdgcn_global_load_lds((const __attribute__((address_space(1))) void*)ga,
        (__attribute__((address_space(3))) void*)&As[buf * 4096 + tid * 8], 16, 0, 0);
    __builtin_amdgcn_global_load_lds((const __attribute__((address_space(1))) void*)gb,
        (__attribute__((address_space(3))) void*)&Bs[buf * 4096 + tid * 8], 16, 0, 0);
    const short* ga2 = A + (size_t)(m0 + srow2) * K + k0 + sslot2 * 8;
    const short* gb2 = B + (size_t)(n0 + srow2) * K + k0 + sslot2 * 8;
    __builtin_amdgcn_global_load_lds((const __attribute__((address_space(1))) void*)ga2,
        (__attribute__((address_space(3))) void*)&As[buf * 4096 + (tid + 256) * 8], 16, 0, 0);
    __builtin_amdgcn_global_load_lds((const __attribute__((address_space(1))) void*)gb2,
        (__attribute__((address_space(3))) void*)&Bs[buf * 4096 + (tid + 256) * 8], 16, 0, 0);
  };

  int ntiles = K >> 5;
  stage(0, 0);
  __syncthreads();
  int cur = 0;
  for (int t = 0; t < ntiles; ++t) {
    if (t + 1 < ntiles) stage(cur ^ 1, (t + 1) << 5);   // prefetch next tile
    shortx8 af[4], bfr[4];
    #pragma unroll
    for (int mi = 0; mi < 4; ++mi)
      af[mi] = *(const shortx8*)&As[cur * 4096 + (wm + mi * 16 + lrow) * 32 + quad * 8];
    #pragma unroll
    for (int ni = 0; ni < 4; ++ni)
      bfr[ni] = *(const shortx8*)&Bs[cur * 4096 + (wn + ni * 16 + lrow) * 32 + quad * 8];
    #pragma unroll
    for (int mi = 0; mi < 4; ++mi)
      #pragma unroll
      for (int ni = 0; ni < 4; ++ni)
        acc[mi][ni] = __builtin_amdgcn_mfma_f32_16x16x32_bf16(af[mi], bfr[ni], acc[mi][ni], 0, 0, 0);
    __syncthreads();          // drains vmcnt(0) AFTER compute: prefetch latency hidden
    cur ^= 1;
  }

  float bcol[4];
  #pragma unroll
  for (int ni = 0; ni < 4; ++ni) bcol[ni] = bias[n0 + wn + ni * 16 + lrow];

  // ---- stage result tile to LDS (all waves, no conditionals; As/Bs dead) ----
  #pragma unroll
  for (int mi = 0; mi < 4; ++mi) {
    #pragma unroll
    for (int r = 0; r < 4; ++r) {
      int rr = wm + mi * 16 + quad * 4 + r;       // row within 128-tile
      #pragma unroll
      for (int ni = 0; ni < 4; ++ni) {
        int col = wn + ni * 16 + lrow;            // col within 128-tile
        float v = acc[mi][ni][r] + bcol[ni];
        if (EPI == 1) v = gelu_f(v);
        cb[rr * 136 + col] = f2bf(v);
      }
    }
  }
  __syncthreads();

  // ---- drain: 16 lanes per row, 8 bf16 each (256B LDS rows, coalesced HBM) ----
  int rbase = tid >> 4, ic = tid & 15;
  if (EPI == 1) {
    #pragma unroll
    for (int v = 0; v < 8; ++v) {
      int rr = v * 16 + rbase;
      shortx8 val = *(const shortx8*)&cb[rr * 136 + ic * 8];
      *(shortx8*)&outb[(size_t)(m0 + rr) * N + n0 + ic * 8] = val;
    }
  } else {
    #pragma unroll
    for (int v = 0; v < 8; ++v) {
      int rr = v * 16 + rbase;
      int tr = m0 + rr;
      shortx8 f8 = *(const shortx8*)&cb[rr * 136 + ic * 8];
      float fv[8];
      #pragma unroll
      for (int j = 0; j < 8; ++j) fv[j] = bf2f(f8[j]);
      const float* xr = x + (size_t)tr * KX + n0 + ic * 8;
      float4 xa[4], xb[4];
      #pragma unroll
      for (int n = 0; n < 4; ++n) {
        xa[n] = *(const float4*)(xr + n * 768);
        xb[n] = *(const float4*)(xr + n * 768 + 4);
      }
      const float4* hrp = (const float4*)(hres + (size_t)tr * 16);
      float4 hp4 = *(const float4*)&hpost[(size_t)tr * 4];
      float hpv[4] = {hp4.x, hp4.y, hp4.z, hp4.w};
      float* orow = out + (size_t)tr * KX + n0 + ic * 8;
      #pragma unroll
      for (int n = 0; n < 4; ++n) {
        float4 h = hrp[n];
        float4 oa, ob;
        oa.x = h.x * xa[0].x + h.y * xa[1].x + h.z * xa[2].x + h.w * xa[3].x + hpv[n] * fv[0];
        oa.y = h.x * xa[0].y + h.y * xa[1].y + h.z * xa[2].y + h.w * xa[3].y + hpv[n] * fv[1];
        oa.z = h.x * xa[0].z + h.y * xa[1].z + h.z * xa[2].z + h.w * xa[3].z + hpv[n] * fv[2];
        oa.w = h.x * xa[0].w + h.y * xa[1].w + h.z * xa[2].w + h.w * xa[3].w + hpv[n] * fv[3];
        ob.x = h.x * xb[0].x + h.y * xb[1].x + h.z * xb[2].x + h.w * xb[3].x + hpv[n] * fv[4];
        ob.y = h.x * xb[0].y + h.y * xb[1].y + h.z * xb[2].y + h.w * xb[3].y + hpv[n] * fv[5];
        ob.z = h.x * xb[0].z + h.y * xb[1].z + h.z * xb[2].z + h.w * xb[3].z + hpv[n] * fv[6];
        ob.w = h.x * xb[0].w + h.y * xb[1].w + h.z * xb[2].w + h.w * xb[3].w + hpv[n] * fv[7];
        *(float4*)(orow + n * 768) = oa;
        *(float4*)(orow + n * 768 + 4) = ob;
      }
    }
  }
}

extern "C" void kernel_launch(void* const* d_in, const int* in_sizes, int n_in,
                              void* d_out, int out_size, void* d_ws, size_t ws_size,
                              hipStream_t stream) {
  const float* x      = (const float*)d_in[0];
  const float* phi    = (const float*)d_in[1];
  const float* b      = (const float*)d_in[2];
  const float* a_pre  = (const float*)d_in[3];
  const float* a_post = (const float*)d_in[4];
  const float* a_res  = (const float*)d_in[5];
  const float* W1     = (const float*)d_in[6];
  const float* b1     = (const float*)d_in[7];
  const float* W2     = (const float*)d_in[8];
  const float* b2     = (const float*)d_in[9];
  float* out = (float*)d_out;

  char* ws = (char*)d_ws;
  size_t off = 0;
  auto carve = [&](size_t bytes) {
    char* p = ws + off;
    off += (bytes + 255) & ~(size_t)255;
    return p;
  };
  short* x_in  = (short*)carve((size_t)NT * C_ * 2);        //  25.2 MB bf16
  short* act   = (short*)carve((size_t)NT * DFF_ * 2);      // 100.7 MB bf16
  float* hpost = (float*)carve((size_t)NT * 4 * 4);
  float* hres  = (float*)carve((size_t)NT * 16 * 4);
  float* hpre  = (float*)carve((size_t)NT * 4 * 4);
  short* W1T   = (short*)carve((size_t)DFF_ * C_ * 2);
  short* W2T   = (short*)carve((size_t)C_ * DFF_ * 2);
  float* phiT  = (float*)carve((size_t)NMIX * KX * 4);
  float* pmix  = (float*)carve((size_t)NT * KSPLIT * NMIX * 4);  // 6.3 MB
  float* pssq  = (float*)carve((size_t)NT * KSPLIT * 4);

  phiT_kernel<<<dim3((KX * NMIX + 255) / 256), 256, 0, stream>>>(phi, phiT);
  transpose_bf16<<<dim3(DFF_ / 32, C_ / 32), 256, 0, stream>>>(W1, W1T, C_, DFF_);
  transpose_bf16<<<dim3(C_ / 32, DFF_ / 32), 256, 0, stream>>>(W2, W2T, DFF_, C_);
  k1a<<<dim3((NT / TB) * KSPLIT), 256, 0, stream>>>(x, phiT, pmix, pssq);
  k1b<<<dim3(NT / TB), 256, 0, stream>>>(pmix, pssq, b, a_pre, a_post, a_res,
                                         hpre, hpost, hres);
  k1c<<<dim3(NT * 192 / 256), 256, 0, stream>>>(x, hpre, x_in);
  gemm_bt<1><<<dim3(DFF_ / 128, NT / 128), 256, 0, stream>>>(
      x_in, W1T, NT, DFF_, C_, b1, act, nullptr, nullptr, nullptr, nullptr);
  gemm_bt<2><<<dim3(C_ / 128, NT / 128), 256, 0, stream>>>(
      act, W2T, NT, C_, DFF_, b2, nullptr, x, hres, hpost, out);
}

// Round 4
// 678.362 us; speedup vs baseline: 1.0561x; 1.0008x over previous
//
#include <hip/hip_runtime.h>
#include <hip/hip_bf16.h>
#include <stdint.h>

#define NT   16384   // tokens = B*S
#define C_   768
#define DFF_ 3072
#define KX   3072    // N*C
#define NMIX 24
#define TB   64
#define KSPLIT 4
#define KSEG (KX / KSPLIT)   // 768

typedef __attribute__((ext_vector_type(8))) short shortx8;
typedef __attribute__((ext_vector_type(4))) float floatx4;

__device__ __forceinline__ short f2bf(float f) {
  union { float f; uint32_t u; } v; v.f = f;
  uint32_t r = v.u + 0x7fffu + ((v.u >> 16) & 1u);   // RNE
  return (short)(r >> 16);
}

__device__ __forceinline__ float bf2f(short s) {
  union { uint32_t u; float f; } v;
  v.u = ((uint32_t)(uint16_t)s) << 16;
  return v.f;
}

// fast gelu: v*sigmoid(1.5957691*(v+0.044715 v^3)); |err| vs erf-gelu ~3e-4
__device__ __forceinline__ float gelu_f(float v) {
  float u = 1.5957691216057308f * v * (1.0f + 0.044715f * v * v);
  return v / (1.0f + __expf(-u));
}

// ---------- prep: phi (3072x24) -> phiT (24x3072) fp32 ----------
__global__ void phiT_kernel(const float* __restrict__ phi, float* __restrict__ phiT) {
  int idx = blockIdx.x * 256 + threadIdx.x;
  if (idx < KX * NMIX) {
    int k = idx / NMIX, j = idx - k * NMIX;
    phiT[(size_t)j * KX + k] = phi[idx];
  }
}

// ---------- prep: fp32 (R x C) -> bf16 transposed (C x R) ----------
__global__ __launch_bounds__(256) void transpose_bf16(const float* __restrict__ in,
                                                      short* __restrict__ out,
                                                      int R, int C) {
  __shared__ float tile[32][33];
  int bx = blockIdx.x * 32;   // C dim
  int by = blockIdx.y * 32;   // R dim
  int tx = threadIdx.x & 31, ty = threadIdx.x >> 5;
  #pragma unroll
  for (int i = 0; i < 32; i += 8)
    tile[ty + i][tx] = in[(size_t)(by + ty + i) * C + bx + tx];
  __syncthreads();
  #pragma unroll
  for (int i = 0; i < 32; i += 8)
    out[(size_t)(bx + ty + i) * R + by + tx] = f2bf(tile[tx][ty + i]);
}

// ---------- k1a: partial mix + partial ssq over a 768-wide k segment ----------
__global__ __launch_bounds__(256) void k1a(
    const float* __restrict__ x, const float* __restrict__ phiT,
    float* __restrict__ pmix, float* __restrict__ pssq) {
  __shared__ float xs[TB][132];     // 128-k chunk, +4 pad
  int tid = threadIdx.x;
  int lane = tid & 63;              // token within block
  int w = tid >> 6;                 // j-group (6 j's per wave)
  int wu = __builtin_amdgcn_readfirstlane(w);
  int t0 = (blockIdx.x >> 2) * TB;
  int slot = blockIdx.x & 3;
  int ks = slot * KSEG;

  float acc[6] = {0.f, 0.f, 0.f, 0.f, 0.f, 0.f};
  float ssq = 0.f;

  for (int kc = ks; kc < ks + KSEG; kc += 128) {
    if (kc != ks) __syncthreads();
    #pragma unroll
    for (int jj = 0; jj < 8; ++jj) {          // stage 64 tokens x 128 k
      int idx = tid + jj * 256;
      int row = idx >> 5, c4 = idx & 31;
      const float4 v = *(const float4*)&x[(size_t)(t0 + row) * KX + kc + c4 * 4];
      *(float4*)&xs[row][c4 * 4] = v;
    }
    __syncthreads();
    #pragma unroll 4
    for (int k4 = 0; k4 < 32; ++k4) {
      const float4 xv = *(const float4*)&xs[lane][k4 * 4];
      if (w == 0) ssq += xv.x * xv.x + xv.y * xv.y + xv.z * xv.z + xv.w * xv.w;
      int kk = kc + k4 * 4;
      #pragma unroll
      for (int jj = 0; jj < 6; ++jj) {        // phi via wave-uniform (scalar) loads
        const float4 p = *(const float4*)&phiT[(size_t)(wu * 6 + jj) * KX + kk];
        acc[jj] += p.x * xv.x + p.y * xv.y + p.z * xv.z + p.w * xv.w;
      }
    }
  }
  if (w == 0) pssq[(size_t)(t0 + lane) * KSPLIT + slot] = ssq;
  #pragma unroll
  for (int jj = 0; jj < 6; ++jj)
    pmix[((size_t)(t0 + lane) * KSPLIT + slot) * NMIX + wu * 6 + jj] = acc[jj];
}

// ---------- k1b: reduce partials + sinkhorn + h_pre/h_post/h_res ----------
__global__ __launch_bounds__(256) void k1b(
    const float* __restrict__ pmix, const float* __restrict__ pssq,
    const float* __restrict__ bvec, const float* __restrict__ a_pre,
    const float* __restrict__ a_post, const float* __restrict__ a_res,
    float* __restrict__ hpre, float* __restrict__ hpost, float* __restrict__ hres) {
  __shared__ float mixs[TB][NMIX];
  __shared__ float invr_s[TB];
  int tid = threadIdx.x;
  int t0 = blockIdx.x * TB;
  int tq = tid >> 2, r = tid & 3;

  {   // thread (tq, r) reduces j-range [r*6, r*6+6) over 4 k-slots
    const float* pm = pmix + (size_t)(t0 + tq) * KSPLIT * NMIX;
    float s[6] = {0.f, 0.f, 0.f, 0.f, 0.f, 0.f};
    #pragma unroll
    for (int sl = 0; sl < KSPLIT; ++sl)
      #pragma unroll
      for (int jj = 0; jj < 6; ++jj)
        s[jj] += pm[sl * NMIX + r * 6 + jj];
    #pragma unroll
    for (int jj = 0; jj < 6; ++jj) mixs[tq][r * 6 + jj] = s[jj];
    if (r == 0) {
      const float* ps = pssq + (size_t)(t0 + tq) * KSPLIT;
      float sq = ps[0] + ps[1] + ps[2] + ps[3];
      invr_s[tq] = rsqrtf(sq * (1.0f / KX) + 1e-6f);
    }
  }
  __syncthreads();

  {  // sinkhorn: thread = (token tq, row r); cols in regs, col-sums via shfl
    float invr = invr_s[tq];
    float ares = a_res[0];
    float v0 = mixs[tq][8 + r * 4 + 0] * invr * ares + bvec[8 + r * 4 + 0];
    float v1 = mixs[tq][8 + r * 4 + 1] * invr * ares + bvec[8 + r * 4 + 1];
    float v2 = mixs[tq][8 + r * 4 + 2] * invr * ares + bvec[8 + r * 4 + 2];
    float v3 = mixs[tq][8 + r * 4 + 3] * invr * ares + bvec[8 + r * 4 + 3];
    float mx = fmaxf(fmaxf(v0, v1), fmaxf(v2, v3));
    v0 = __expf(v0 - mx); v1 = __expf(v1 - mx); v2 = __expf(v2 - mx); v3 = __expf(v3 - mx);
    for (int it = 0; it < 20; ++it) {
      float s = v0 + v1 + v2 + v3 + 1e-6f;    // row normalize (ref adds eps to sum)
      float inv = 1.0f / s;
      v0 *= inv; v1 *= inv; v2 *= inv; v3 *= inv;
      float c0 = v0 + __shfl_xor(v0, 1); c0 += __shfl_xor(c0, 2);
      float c1 = v1 + __shfl_xor(v1, 1); c1 += __shfl_xor(c1, 2);
      float c2 = v2 + __shfl_xor(v2, 1); c2 += __shfl_xor(c2, 2);
      float c3 = v3 + __shfl_xor(v3, 1); c3 += __shfl_xor(c3, 2);
      v0 /= (c0 + 1e-6f); v1 /= (c1 + 1e-6f); v2 /= (c2 + 1e-6f); v3 /= (c3 + 1e-6f);
    }
    float* ho = hres + (size_t)(t0 + tq) * 16 + r * 4;
    ho[0] = v0; ho[1] = v1; ho[2] = v2; ho[3] = v3;
    if (r == 0) {
      float apre = a_pre[0];
      float4 hp;
      hp.x = 1.0f / (1.0f + __expf(-(mixs[tq][0] * invr * apre + bvec[0])));
      hp.y = 1.0f / (1.0f + __expf(-(mixs[tq][1] * invr * apre + bvec[1])));
      hp.z = 1.0f / (1.0f + __expf(-(mixs[tq][2] * invr * apre + bvec[2])));
      hp.w = 1.0f / (1.0f + __expf(-(mixs[tq][3] * invr * apre + bvec[3])));
      *(float4*)&hpre[(size_t)(t0 + tq) * 4] = hp;
    } else if (r == 1) {
      float apost = a_post[0];
      float4 hq;
      hq.x = 2.0f / (1.0f + __expf(-(mixs[tq][4] * invr * apost + bvec[4])));
      hq.y = 2.0f / (1.0f + __expf(-(mixs[tq][5] * invr * apost + bvec[5])));
      hq.z = 2.0f / (1.0f + __expf(-(mixs[tq][6] * invr * apost + bvec[6])));
      hq.w = 2.0f / (1.0f + __expf(-(mixs[tq][7] * invr * apost + bvec[7])));
      *(float4*)&hpost[(size_t)(t0 + tq) * 4] = hq;
    }
  }
}

// ---------- k1c: x_in[t][c] = sum_n hpre[t][n] * x[t][n*768+c], bf16 out ----------
__global__ __launch_bounds__(256) void k1c(
    const float* __restrict__ x, const float* __restrict__ hpre,
    short* __restrict__ x_in) {
  int idx = blockIdx.x * 256 + threadIdx.x;   // NT*192 float4-groups
  int t = idx / 192;
  int c = (idx - t * 192) * 4;
  float4 hp = *(const float4*)&hpre[(size_t)t * 4];
  const float* xr = x + (size_t)t * KX + c;
  float4 x0 = *(const float4*)(xr);
  float4 x1 = *(const float4*)(xr + C_);
  float4 x2 = *(const float4*)(xr + 2 * C_);
  float4 x3 = *(const float4*)(xr + 3 * C_);
  short4 s;
  s.x = f2bf(hp.x * x0.x + hp.y * x1.x + hp.z * x2.x + hp.w * x3.x);
  s.y = f2bf(hp.x * x0.y + hp.y * x1.y + hp.z * x2.y + hp.w * x3.y);
  s.z = f2bf(hp.x * x0.z + hp.y * x1.z + hp.z * x2.z + hp.w * x3.z);
  s.w = f2bf(hp.x * x0.w + hp.y * x1.w + hp.z * x2.w + hp.w * x3.w);
  *(short4*)&x_in[(size_t)t * C_ + c] = s;
}

// ---------- bf16 GEMM, B^T input, 3-buffer K-loop with counted vmcnt ----------
// T4: never drain vmcnt to 0 in the main loop. Prefetch distance 2; raw
// s_barrier + s_waitcnt vmcnt(4) keeps the newest tile's 4 global_load_lds
// in flight across the barrier (~2 iterations of latency cover).
// Race audit: stage(t+2) overwrites tile t-1's buffer — all waves finished
// ds_reads of t-1 (lgkmcnt(0)) before the iter t-1 trailing barrier, which
// precedes this stage. Trailing vmcnt(4) retires exactly tile t+1 (vmcnt is
// issue-ordered; max 8 outstanding). Penultimate iter waits vmcnt(0) so the
// epilogue LDS union starts with zero in-flight DMA.
// EPI=1: act = gelu(A@B^T + bias), bf16, shortx8 stores
// EPI=2: out[t,n,:] = hres@x + hpost*(A@B^T + bias), f32, float4 I/O
template <int EPI>
__global__ __launch_bounds__(256, 3) void gemm_bt(
    const short* __restrict__ A, const short* __restrict__ B,
    int M, int N, int K, const float* __restrict__ bias,
    short* __restrict__ outb,
    const float* __restrict__ x, const float* __restrict__ hres,
    const float* __restrict__ hpost, float* __restrict__ out) {
  __shared__ __align__(16) char smem[49152];       // 3-buf As/Bs (48K) ∪ cb (34.8K)
  short* As = (short*)smem;                        // [3][4096] bf16
  short* Bs = (short*)(smem + 24576);              // [3][4096] bf16
  short* cb = (short*)smem;                        // epilogue 128x136 bf16
  int tid = threadIdx.x;
  int lane = tid & 63, w = tid >> 6;
  // XCD-chunked swizzle: consecutive lids (sharing the A-panel) on one XCD.
  int nwg = gridDim.x * gridDim.y;                 // 3072 / 768, both %8==0
  int lid = blockIdx.y * gridDim.x + blockIdx.x;
  int sid = (lid & 7) * (nwg >> 3) + (lid >> 3);   // bijective for nwg%8==0
  int bx = sid % gridDim.x, by = sid / gridDim.x;
  int m0 = by * 128, n0 = bx * 128;
  int wm = (w >> 1) * 64, wn = (w & 1) * 64;
  int lrow = lane & 15, quad = lane >> 4;
  floatx4 acc[4][4] = {};

  int srow = tid >> 2, sslot = tid & 3;            // staging: thread -> (row, 8-elem slot)
  int srow2 = (tid + 256) >> 2, sslot2 = (tid + 256) & 3;

  auto stage = [&](int buf, int t) {               // issues exactly 4 global_load_lds
    int k0 = t << 5;
    int bo = buf << 12;                            // buf * 4096 shorts
    const short* ga = A + (size_t)(m0 + srow) * K + k0 + sslot * 8;
    const short* gb = B + (size_t)(n0 + srow) * K + k0 + sslot * 8;
    __builtin_amdgcn_global_load_lds((const __attribute__((address_space(1))) void*)ga,
        (__attribute__((address_space(3))) void*)&As[bo + tid * 8], 16, 0, 0);
    __builtin_amdgcn_global_load_lds((const __attribute__((address_space(1))) void*)gb,
        (__attribute__((address_space(3))) void*)&Bs[bo + tid * 8], 16, 0, 0);
    const short* ga2 = A + (size_t)(m0 + srow2) * K + k0 + sslot2 * 8;
    const short* gb2 = B + (size_t)(n0 + srow2) * K + k0 + sslot2 * 8;
    __builtin_amdgcn_global_load_lds((const __attribute__((address_space(1))) void*)ga2,
        (__attribute__((address_space(3))) void*)&As[bo + (tid + 256) * 8], 16, 0, 0);
    __builtin_amdgcn_global_load_lds((const __attribute__((address_space(1))) void*)gb2,
        (__attribute__((address_space(3))) void*)&Bs[bo + (tid + 256) * 8], 16, 0, 0);
  };

  int ntiles = K >> 5;
  stage(0, 0);
  stage(1, 1);
  asm volatile("s_waitcnt vmcnt(4)" ::: "memory");   // tile 0 landed (this wave)
  __builtin_amdgcn_s_barrier();                      // -> landed for all waves
  int cur = 0, pf = 2;
  for (int t = 0; t < ntiles; ++t) {
    bool do_pf = (t + 2 < ntiles);
    shortx8 af[4], bfr[4];
    {
      int co = cur << 12;
      #pragma unroll
      for (int mi = 0; mi < 4; ++mi)
        af[mi] = *(const shortx8*)&As[co + (wm + mi * 16 + lrow) * 32 + quad * 8];
      #pragma unroll
      for (int ni = 0; ni < 4; ++ni)
        bfr[ni] = *(const shortx8*)&Bs[co + (wn + ni * 16 + lrow) * 32 + quad * 8];
    }
    if (do_pf) stage(pf, t + 2);                   // overwrite tile t-1's buffer
    asm volatile("s_waitcnt lgkmcnt(0)" ::: "memory");
    __builtin_amdgcn_sched_barrier(0);             // rule #18: pin MFMA after lgkmcnt
    #pragma unroll
    for (int mi = 0; mi < 4; ++mi)
      #pragma unroll
      for (int ni = 0; ni < 4; ++ni)
        acc[mi][ni] = __builtin_amdgcn_mfma_f32_16x16x32_bf16(af[mi], bfr[ni], acc[mi][ni], 0, 0, 0);
    if (t + 1 < ntiles) {
      if (do_pf) asm volatile("s_waitcnt vmcnt(4)" ::: "memory");   // tile t+1 landed
      else       asm volatile("s_waitcnt vmcnt(0)" ::: "memory");   // full drain pre-epilogue
      __builtin_amdgcn_s_barrier();
    }
    cur = (cur == 2) ? 0 : cur + 1;
    pf  = (pf  == 2) ? 0 : pf  + 1;
  }
  __syncthreads();   // LDS union handoff (vm already drained; all ds_reads done)

  float bcol[4];
  #pragma unroll
  for (int ni = 0; ni < 4; ++ni) bcol[ni] = bias[n0 + wn + ni * 16 + lrow];

  // ---- stage result tile to LDS (all waves, no conditionals; As/Bs dead) ----
  #pragma unroll
  for (int mi = 0; mi < 4; ++mi) {
    #pragma unroll
    for (int r = 0; r < 4; ++r) {
      int rr = wm + mi * 16 + quad * 4 + r;       // row within 128-tile
      #pragma unroll
      for (int ni = 0; ni < 4; ++ni) {
        int col = wn + ni * 16 + lrow;            // col within 128-tile
        float v = acc[mi][ni][r] + bcol[ni];
        if (EPI == 1) v = gelu_f(v);
        cb[rr * 136 + col] = f2bf(v);
      }
    }
  }
  __syncthreads();

  // ---- drain: 16 lanes per row, 8 bf16 each (256B LDS rows, coalesced HBM) ----
  int rbase = tid >> 4, ic = tid & 15;
  if (EPI == 1) {
    #pragma unroll
    for (int v = 0; v < 8; ++v) {
      int rr = v * 16 + rbase;
      shortx8 val = *(const shortx8*)&cb[rr * 136 + ic * 8];
      *(shortx8*)&outb[(size_t)(m0 + rr) * N + n0 + ic * 8] = val;
    }
  } else {
    #pragma unroll
    for (int v = 0; v < 8; ++v) {
      int rr = v * 16 + rbase;
      int tr = m0 + rr;
      shortx8 f8 = *(const shortx8*)&cb[rr * 136 + ic * 8];
      float fv[8];
      #pragma unroll
      for (int j = 0; j < 8; ++j) fv[j] = bf2f(f8[j]);
      const float* xr = x + (size_t)tr * KX + n0 + ic * 8;
      float4 xa[4], xb[4];
      #pragma unroll
      for (int n = 0; n < 4; ++n) {
        xa[n] = *(const float4*)(xr + n * 768);
        xb[n] = *(const float4*)(xr + n * 768 + 4);
      }
      const float4* hrp = (const float4*)(hres + (size_t)tr * 16);
      float4 hp4 = *(const float4*)&hpost[(size_t)tr * 4];
      float hpv[4] = {hp4.x, hp4.y, hp4.z, hp4.w};
      float* orow = out + (size_t)tr * KX + n0 + ic * 8;
      #pragma unroll
      for (int n = 0; n < 4; ++n) {
        float4 h = hrp[n];
        float4 oa, ob;
        oa.x = h.x * xa[0].x + h.y * xa[1].x + h.z * xa[2].x + h.w * xa[3].x + hpv[n] * fv[0];
        oa.y = h.x * xa[0].y + h.y * xa[1].y + h.z * xa[2].y + h.w * xa[3].y + hpv[n] * fv[1];
        oa.z = h.x * xa[0].z + h.y * xa[1].z + h.z * xa[2].z + h.w * xa[3].z + hpv[n] * fv[2];
        oa.w = h.x * xa[0].w + h.y * xa[1].w + h.z * xa[2].w + h.w * xa[3].w + hpv[n] * fv[3];
        ob.x = h.x * xb[0].x + h.y * xb[1].x + h.z * xb[2].x + h.w * xb[3].x + hpv[n] * fv[4];
        ob.y = h.x * xb[0].y + h.y * xb[1].y + h.z * xb[2].y + h.w * xb[3].y + hpv[n] * fv[5];
        ob.z = h.x * xb[0].z + h.y * xb[1].z + h.z * xb[2].z + h.w * xb[3].z + hpv[n] * fv[6];
        ob.w = h.x * xb[0].w + h.y * xb[1].w + h.z * xb[2].w + h.w * xb[3].w + hpv[n] * fv[7];
        *(float4*)(orow + n * 768) = oa;
        *(float4*)(orow + n * 768 + 4) = ob;
      }
    }
  }
}

extern "C" void kernel_launch(void* const* d_in, const int* in_sizes, int n_in,
                              void* d_out, int out_size, void* d_ws, size_t ws_size,
                              hipStream_t stream) {
  const float* x      = (const float*)d_in[0];
  const float* phi    = (const float*)d_in[1];
  const float* b      = (const float*)d_in[2];
  const float* a_pre  = (const float*)d_in[3];
  const float* a_post = (const float*)d_in[4];
  const float* a_res  = (const float*)d_in[5];
  const float* W1     = (const float*)d_in[6];
  const float* b1     = (const float*)d_in[7];
  const float* W2     = (const float*)d_in[8];
  const float* b2     = (const float*)d_in[9];
  float* out = (float*)d_out;

  char* ws = (char*)d_ws;
  size_t off = 0;
  auto carve = [&](size_t bytes) {
    char* p = ws + off;
    off += (bytes + 255) & ~(size_t)255;
    return p;
  };
  short* x_in  = (short*)carve((size_t)NT * C_ * 2);        //  25.2 MB bf16
  short* act   = (short*)carve((size_t)NT * DFF_ * 2);      // 100.7 MB bf16
  float* hpost = (float*)carve((size_t)NT * 4 * 4);
  float* hres  = (float*)carve((size_t)NT * 16 * 4);
  float* hpre  = (float*)carve((size_t)NT * 4 * 4);
  short* W1T   = (short*)carve((size_t)DFF_ * C_ * 2);
  short* W2T   = (short*)carve((size_t)C_ * DFF_ * 2);
  float* phiT  = (float*)carve((size_t)NMIX * KX * 4);
  float* pmix  = (float*)carve((size_t)NT * KSPLIT * NMIX * 4);  // 6.3 MB
  float* pssq  = (float*)carve((size_t)NT * KSPLIT * 4);

  phiT_kernel<<<dim3((KX * NMIX + 255) / 256), 256, 0, stream>>>(phi, phiT);
  transpose_bf16<<<dim3(DFF_ / 32, C_ / 32), 256, 0, stream>>>(W1, W1T, C_, DFF_);
  transpose_bf16<<<dim3(C_ / 32, DFF_ / 32), 256, 0, stream>>>(W2, W2T, DFF_, C_);
  k1a<<<dim3((NT / TB) * KSPLIT), 256, 0, stream>>>(x, phiT, pmix, pssq);
  k1b<<<dim3(NT / TB), 256, 0, stream>>>(pmix, pssq, b, a_pre, a_post, a_res,
                                         hpre, hpost, hres);
  k1c<<<dim3(NT * 192 / 256), 256, 0, stream>>>(x, hpre, x_in);
  gemm_bt<1><<<dim3(DFF_ / 128, NT / 128), 256, 0, stream>>>(
      x_in, W1T, NT, DFF_, C_, b1, act, nullptr, nullptr, nullptr, nullptr);
  gemm_bt<2><<<dim3(C_ / 128, NT / 128), 256, 0, stream>>>(
      act, W2T, NT, C_, DFF_, b2, nullptr, x, hres, hpost, out);
}